// Round 4
// baseline (98.402 us; speedup 1.0000x reference)
//
#include <hip/hip_runtime.h>
#include <math.h>

#define QN  4
#define CN  256
#define BN  32
#define NN  4096
#define SPB 16           // blocks per batch
#define WV  4            // waves per block
#define RPW 64           // rows per wave  (= NN/(SPB*WV))
#define NG  16           // 4-row groups per wave

// ---------------------------------------------------------------------------
// Fused single-pass: scores bounded (|s| <= ||q||*||h||/16 ~ 16), so softmax
// needs no running max: accumulate l = sum(exp s), acc = sum(exp s * h_row).
// 16-lane subgroup per row (4 rows/wave-group); lane owns 16 channels as
// 4 x float4 at stride 64 -> coalesced 256B segments; masked rows skipped by
// exec mask (HBM saving). No LDS in main loop; 1-deep register prefetch.
// grid = BN*SPB = 512 blocks x 256 threads.
// ---------------------------------------------------------------------------
__global__ __launch_bounds__(256, 2) void k_fused(
    const float* __restrict__ h, const int* __restrict__ mask,
    const float* __restrict__ qr,
    float* __restrict__ P, float* __restrict__ L)
{
    const int b    = blockIdx.x >> 4;
    const int sub  = blockIdx.x & 15;
    const int w    = threadIdx.x >> 6;
    const int lane = threadIdx.x & 63;
    const int l15  = lane & 15;     // channel sub-block
    const int rg   = lane >> 4;     // row within 4-row group

    const int n0    = (sub * WV + w) * RPW;
    const size_t gn = (size_t)b * NN + n0;
    const float* __restrict__ hb = h + gn * CN;

    // query fragments for this lane's channels (scale folded in)
    float4 q4[QN][4];
#pragma unroll
    for (int q = 0; q < QN; ++q)
#pragma unroll
        for (int j = 0; j < 4; ++j) {
            float4 t = *(const float4*)(qr + q * CN + j * 64 + l15 * 4);
            t.x *= 0.0625f; t.y *= 0.0625f; t.z *= 0.0625f; t.w *= 0.0625f;
            q4[q][j] = t;
        }

    // mask bits for this wave's 64 rows (one ballot)
    const unsigned long long mb = __ballot(mask[gn + lane] != 0);

    float4 acc[QN][4];
    float  lsum[QN];
#pragma unroll
    for (int q = 0; q < QN; ++q) {
        lsum[q] = 0.f;
#pragma unroll
        for (int j = 0; j < 4; ++j) acc[q][j] = make_float4(0.f, 0.f, 0.f, 0.f);
    }

    // ---- prologue: load group 0 ----
    float4 v[4] = {make_float4(0,0,0,0), make_float4(0,0,0,0),
                   make_float4(0,0,0,0), make_float4(0,0,0,0)};
    bool act = !((mb >> rg) & 1ull);
    if (act) {
        const float* hr = hb + (size_t)rg * CN + l15 * 4;
        v[0] = *(const float4*)(hr +   0);
        v[1] = *(const float4*)(hr +  64);
        v[2] = *(const float4*)(hr + 128);
        v[3] = *(const float4*)(hr + 192);
    }

#pragma unroll
    for (int g = 0; g < NG; ++g) {
        // ---- prefetch next group ----
        float4 vn[4] = {make_float4(0,0,0,0), make_float4(0,0,0,0),
                        make_float4(0,0,0,0), make_float4(0,0,0,0)};
        bool actn = false;
        if (g + 1 < NG) {
            const int rn = (g + 1) * 4 + rg;
            actn = !((mb >> rn) & 1ull);
            if (actn) {
                const float* hr = hb + (size_t)rn * CN + l15 * 4;
                vn[0] = *(const float4*)(hr +   0);
                vn[1] = *(const float4*)(hr +  64);
                vn[2] = *(const float4*)(hr + 128);
                vn[3] = *(const float4*)(hr + 192);
            }
        }

        // ---- dot: lane's 16-channel partial for 4 queries ----
        float s[QN] = {0.f, 0.f, 0.f, 0.f};
#pragma unroll
        for (int q = 0; q < QN; ++q) {
#pragma unroll
            for (int j = 0; j < 4; ++j) {
                s[q] += v[j].x * q4[q][j].x + v[j].y * q4[q][j].y
                      + v[j].z * q4[q][j].z + v[j].w * q4[q][j].w;
            }
        }
        // reduce across the 16-lane subgroup (xor 1,2,4,8)
#pragma unroll
        for (int off = 1; off <= 8; off <<= 1)
#pragma unroll
            for (int q = 0; q < QN; ++q)
                s[q] += __shfl_xor(s[q], off, 64);

        float p[QN];
#pragma unroll
        for (int q = 0; q < QN; ++q) p[q] = act ? __expf(s[q]) : 0.f;

        // ---- pool: acc += p * v for this lane's channels; l += p ----
#pragma unroll
        for (int q = 0; q < QN; ++q) {
            lsum[q] += p[q];
#pragma unroll
            for (int j = 0; j < 4; ++j) {
                acc[q][j].x += p[q] * v[j].x;
                acc[q][j].y += p[q] * v[j].y;
                acc[q][j].z += p[q] * v[j].z;
                acc[q][j].w += p[q] * v[j].w;
            }
        }

        // rotate pipeline
#pragma unroll
        for (int j = 0; j < 4; ++j) v[j] = vn[j];
        act = actn;
    }

    // ---- combine the 4 row-subgroups within the wave (xor 16, 32) ----
#pragma unroll
    for (int q = 0; q < QN; ++q) {
#pragma unroll
        for (int j = 0; j < 4; ++j) {
            acc[q][j].x += __shfl_xor(acc[q][j].x, 16, 64);
            acc[q][j].y += __shfl_xor(acc[q][j].y, 16, 64);
            acc[q][j].z += __shfl_xor(acc[q][j].z, 16, 64);
            acc[q][j].w += __shfl_xor(acc[q][j].w, 16, 64);
            acc[q][j].x += __shfl_xor(acc[q][j].x, 32, 64);
            acc[q][j].y += __shfl_xor(acc[q][j].y, 32, 64);
            acc[q][j].z += __shfl_xor(acc[q][j].z, 32, 64);
            acc[q][j].w += __shfl_xor(acc[q][j].w, 32, 64);
        }
        lsum[q] += __shfl_xor(lsum[q], 16, 64);
        lsum[q] += __shfl_xor(lsum[q], 32, 64);
    }

    // ---- block combine via LDS, write per-block partials ----
    __shared__ float s_part[WV][QN * CN];  // 16 KB
    __shared__ float s_lp[WV][QN];
    if (lane < 16) {
#pragma unroll
        for (int q = 0; q < QN; ++q)
#pragma unroll
            for (int j = 0; j < 4; ++j)
                *(float4*)&s_part[w][q * CN + j * 64 + l15 * 4] = acc[q][j];
    }
    if (lane == 0) {
#pragma unroll
        for (int q = 0; q < QN; ++q) s_lp[w][q] = lsum[q];
    }
    __syncthreads();

    {
        const int t = threadIdx.x;  // 256 threads x float4 = 1024 floats
        float4 o = make_float4(0.f, 0.f, 0.f, 0.f);
#pragma unroll
        for (int ww = 0; ww < WV; ++ww) {
            const float4 tv = *(const float4*)&s_part[ww][t * 4];
            o.x += tv.x; o.y += tv.y; o.z += tv.z; o.w += tv.w;
        }
        ((float4*)(P + (size_t)blockIdx.x * (QN * CN)))[t] = o;
        if (t < QN)
            L[blockIdx.x * QN + t] =
                s_lp[0][t] + s_lp[1][t] + s_lp[2][t] + s_lp[3][t];
    }
}

// ---------------------------------------------------------------------------
// Combine SPB block-partials per batch and divide by l (0 if l==0).
// grid = BN blocks x 256 threads; thread = float4 of [q][c].
// ---------------------------------------------------------------------------
__global__ __launch_bounds__(256) void k_div(
    const float* __restrict__ P, const float* __restrict__ L,
    float* __restrict__ out)
{
    const int b = blockIdx.x;
    const int t = threadIdx.x;
    const int q = t >> 6;

    float4 o = make_float4(0.f, 0.f, 0.f, 0.f);
    float  l = 0.f;
#pragma unroll
    for (int s = 0; s < SPB; ++s) {
        const float4 pv =
            ((const float4*)(P + (size_t)(b * SPB + s) * (QN * CN)))[t];
        o.x += pv.x; o.y += pv.y; o.z += pv.z; o.w += pv.w;
        l += L[(b * SPB + s) * QN + q];
    }
    const float inv = (l > 0.f) ? 1.f / l : 0.f;
    o.x *= inv; o.y *= inv; o.z *= inv; o.w *= inv;
    ((float4*)(out + (size_t)b * (QN * CN)))[t] = o;
}

extern "C" void kernel_launch(void* const* d_in, const int* in_sizes, int n_in,
                              void* d_out, int out_size, void* d_ws, size_t ws_size,
                              hipStream_t stream) {
    const float* h    = (const float*)d_in[0];
    const int*   mask = (const int*)d_in[1];
    const float* qr   = (const float*)d_in[2];
    float*       out  = (float*)d_out;

    float* P = (float*)d_ws;                            // [512][Q*C] = 2 MB
    float* L = P + (size_t)BN * SPB * QN * CN;          // [512][Q]   = 8 KB

    k_fused<<<BN * SPB, 256, 0, stream>>>(h, mask, qr, P, L);
    k_div  <<<BN, 256, 0, stream>>>(P, L, out);
}

// Round 5
// 53.857 us; speedup vs baseline: 1.8271x; 1.8271x over previous
//
#include <hip/hip_runtime.h>
#include <math.h>

#define QN  4
#define CN  256
#define BN  32
#define NN  4096
#define SPB 32           // blocks per batch
#define WV  4            // waves per block
#define RPW 32           // rows per wave  (= NN/(SPB*WV))
#define NG  16           // 2-row groups per wave

// ---------------------------------------------------------------------------
// Fused single-pass: scores bounded (|s| <= ||q||*||h||/16 ~ 16), so softmax
// needs no running max: accumulate l = sum(exp s), acc = sum(exp s * h_row).
// 32-lane subgroup per row (2 rows per wave-group); lane owns 8 channels as
// 2 x float4 (c = 4*l31 and 128+4*l31) -> coalesced 512B segments; masked
// rows skipped via exec mask (HBM saving).  ~105 VGPR -> no spill, 4 w/SIMD.
// grid = BN*SPB = 1024 blocks x 256 threads.
// ---------------------------------------------------------------------------
__global__ __launch_bounds__(256) void k_fused(
    const float* __restrict__ h, const int* __restrict__ mask,
    const float* __restrict__ qr,
    float* __restrict__ P, float* __restrict__ L)
{
    const int b    = blockIdx.x >> 5;
    const int sub  = blockIdx.x & 31;
    const int w    = threadIdx.x >> 6;
    const int lane = threadIdx.x & 63;
    const int l31  = lane & 31;     // channel sub-block
    const int rg   = lane >> 5;     // row within 2-row group

    const int n0    = (sub * WV + w) * RPW;
    const size_t gn = (size_t)b * NN + n0;
    const float* __restrict__ hb = h + gn * CN + l31 * 4;

    // query fragments for this lane's 8 channels (scale folded in)
    float4 q4[QN][2];
#pragma unroll
    for (int q = 0; q < QN; ++q)
#pragma unroll
        for (int j = 0; j < 2; ++j) {
            float4 t = *(const float4*)(qr + q * CN + j * 128 + l31 * 4);
            t.x *= 0.0625f; t.y *= 0.0625f; t.z *= 0.0625f; t.w *= 0.0625f;
            q4[q][j] = t;
        }

    // mask bits for this wave's 32 rows (lanes >=32 contribute dummy 'masked')
    const unsigned long long mb =
        __ballot(lane < RPW ? (mask[gn + lane] != 0) : true);

    float4 acc[QN][2];
    float  lsum[QN];
#pragma unroll
    for (int q = 0; q < QN; ++q) {
        lsum[q] = 0.f;
        acc[q][0] = make_float4(0.f, 0.f, 0.f, 0.f);
        acc[q][1] = make_float4(0.f, 0.f, 0.f, 0.f);
    }

    // ---- prologue: load group 0 (rows rg, rg+1... i.e. row = rg) ----
    float4 v[2] = {make_float4(0,0,0,0), make_float4(0,0,0,0)};
    bool act = !((mb >> rg) & 1ull);
    if (act) {
        const float* hr = hb + (size_t)rg * CN;
        v[0] = *(const float4*)(hr +   0);
        v[1] = *(const float4*)(hr + 128);
    }

#pragma unroll
    for (int g = 0; g < NG; ++g) {
        // ---- prefetch next group ----
        float4 vn[2] = {make_float4(0,0,0,0), make_float4(0,0,0,0)};
        bool actn = false;
        if (g + 1 < NG) {
            const int rn = (g + 1) * 2 + rg;
            actn = !((mb >> rn) & 1ull);
            if (actn) {
                const float* hr = hb + (size_t)rn * CN;
                vn[0] = *(const float4*)(hr +   0);
                vn[1] = *(const float4*)(hr + 128);
            }
        }

        // ---- dot: lane's 8-channel partial for 4 queries ----
        float s[QN];
#pragma unroll
        for (int q = 0; q < QN; ++q) {
            s[q] = v[0].x * q4[q][0].x + v[0].y * q4[q][0].y
                 + v[0].z * q4[q][0].z + v[0].w * q4[q][0].w
                 + v[1].x * q4[q][1].x + v[1].y * q4[q][1].y
                 + v[1].z * q4[q][1].z + v[1].w * q4[q][1].w;
        }
        // reduce across the 32-lane subgroup (xor 1..16; halves independent)
#pragma unroll
        for (int off = 1; off <= 16; off <<= 1)
#pragma unroll
            for (int q = 0; q < QN; ++q)
                s[q] += __shfl_xor(s[q], off, 64);

        float p[QN];
#pragma unroll
        for (int q = 0; q < QN; ++q) p[q] = act ? __expf(s[q]) : 0.f;

        // ---- pool: acc += p * v for this lane's channels; l += p ----
#pragma unroll
        for (int q = 0; q < QN; ++q) {
            lsum[q] += p[q];
            acc[q][0].x += p[q] * v[0].x; acc[q][0].y += p[q] * v[0].y;
            acc[q][0].z += p[q] * v[0].z; acc[q][0].w += p[q] * v[0].w;
            acc[q][1].x += p[q] * v[1].x; acc[q][1].y += p[q] * v[1].y;
            acc[q][1].z += p[q] * v[1].z; acc[q][1].w += p[q] * v[1].w;
        }

        // rotate pipeline
        v[0] = vn[0]; v[1] = vn[1];
        act = actn;
    }

    // ---- combine the two 32-lane halves (same channels, different rows) ----
#pragma unroll
    for (int q = 0; q < QN; ++q) {
#pragma unroll
        for (int j = 0; j < 2; ++j) {
            acc[q][j].x += __shfl_xor(acc[q][j].x, 32, 64);
            acc[q][j].y += __shfl_xor(acc[q][j].y, 32, 64);
            acc[q][j].z += __shfl_xor(acc[q][j].z, 32, 64);
            acc[q][j].w += __shfl_xor(acc[q][j].w, 32, 64);
        }
        lsum[q] += __shfl_xor(lsum[q], 32, 64);
    }

    // ---- block combine via LDS, write per-block partials ----
    __shared__ float s_part[WV][QN * CN];  // 16 KB
    __shared__ float s_lp[WV][QN];
    if (lane < 32) {
#pragma unroll
        for (int q = 0; q < QN; ++q) {
            *(float4*)&s_part[w][q * CN +       l31 * 4] = acc[q][0];
            *(float4*)&s_part[w][q * CN + 128 + l31 * 4] = acc[q][1];
        }
    }
    if (lane == 0) {
#pragma unroll
        for (int q = 0; q < QN; ++q) s_lp[w][q] = lsum[q];
    }
    __syncthreads();

    {
        const int t = threadIdx.x;  // 256 threads x float4 = 1024 floats
        float4 o = make_float4(0.f, 0.f, 0.f, 0.f);
#pragma unroll
        for (int ww = 0; ww < WV; ++ww) {
            const float4 tv = *(const float4*)&s_part[ww][t * 4];
            o.x += tv.x; o.y += tv.y; o.z += tv.z; o.w += tv.w;
        }
        ((float4*)(P + (size_t)blockIdx.x * (QN * CN)))[t] = o;
        if (t < QN)
            L[blockIdx.x * QN + t] =
                s_lp[0][t] + s_lp[1][t] + s_lp[2][t] + s_lp[3][t];
    }
}

// ---------------------------------------------------------------------------
// Combine SPB block-partials per batch and divide by l (0 if l==0).
// grid = BN blocks x 256 threads; thread = float4 of [q][c].
// ---------------------------------------------------------------------------
__global__ __launch_bounds__(256) void k_div(
    const float* __restrict__ P, const float* __restrict__ L,
    float* __restrict__ out)
{
    const int b = blockIdx.x;
    const int t = threadIdx.x;
    const int q = t >> 6;

    float4 o = make_float4(0.f, 0.f, 0.f, 0.f);
    float  l = 0.f;
#pragma unroll 4
    for (int s = 0; s < SPB; ++s) {
        const float4 pv =
            ((const float4*)(P + (size_t)(b * SPB + s) * (QN * CN)))[t];
        o.x += pv.x; o.y += pv.y; o.z += pv.z; o.w += pv.w;
        l += L[(b * SPB + s) * QN + q];
    }
    const float inv = (l > 0.f) ? 1.f / l : 0.f;
    o.x *= inv; o.y *= inv; o.z *= inv; o.w *= inv;
    ((float4*)(out + (size_t)b * (QN * CN)))[t] = o;
}

extern "C" void kernel_launch(void* const* d_in, const int* in_sizes, int n_in,
                              void* d_out, int out_size, void* d_ws, size_t ws_size,
                              hipStream_t stream) {
    const float* h    = (const float*)d_in[0];
    const int*   mask = (const int*)d_in[1];
    const float* qr   = (const float*)d_in[2];
    float*       out  = (float*)d_out;

    float* P = (float*)d_ws;                            // [1024][Q*C] = 4 MB
    float* L = P + (size_t)BN * SPB * QN * CN;          // [1024][Q]   = 16 KB

    k_fused<<<BN * SPB, 256, 0, stream>>>(h, mask, qr, P, L);
    k_div  <<<BN, 256, 0, stream>>>(P, L, out);
}

// Round 6
// 28.515 us; speedup vs baseline: 3.4509x; 1.8887x over previous
//
#include <hip/hip_runtime.h>
#include <math.h>

#define QN  4
#define CN  256
#define BN  32
#define NN  4096
#define WV  4            // waves per block
#define RPW 64           // rows per wave
#define TR  8            // rows per tile
#define NT  8            // tiles per wave (RPW/TR)
#define SPB 16           // blocks per batch (NN/(WV*RPW))

// Load tile tt's 8 rows into vst registers (lane's float4 = channels lane*4..);
// masked rows (scalar branch) become zeros -> no garbage/NaN downstream.
#define LOADT(tt) do {                                                   \
    _Pragma("unroll")                                                    \
    for (int j_ = 0; j_ < TR; ++j_) {                                    \
        const int rw_ = (tt) * TR + j_;                                  \
        if (!((mbits >> rw_) & 1ull))                                    \
            vst[j_] = *(const float4*)(hb + (size_t)rw_ * CN + lane * 4);\
        else                                                             \
            vst[j_] = make_float4(0.f, 0.f, 0.f, 0.f);                   \
    }                                                                    \
} while (0)

#define STORET(bp) do {                                                  \
    _Pragma("unroll")                                                    \
    for (int j_ = 0; j_ < TR; ++j_)                                      \
        *(float4*)((bp) + j_ * CN + lane * 4) = vst[j_];                 \
} while (0)

// ---------------------------------------------------------------------------
// Fused single-pass (no-max softmax: |s|<=~16, fp32 headroom huge).
// Per wave: 64 rows in 8-row LDS tiles, double-buffered, reg-staged 2-deep.
// Score: 16 lanes/row x 16 interleaved channels -> 4-step shuffle per 4 rows.
// Pool: lane owns channels 4*lane.., p broadcast from per-wave LDS pbuf.
// grid = BN*SPB = 512 blocks x 256 threads; LDS ~64.6 KB -> 2 blocks/CU.
// ---------------------------------------------------------------------------
__global__ __launch_bounds__(256) void k_fused(
    const float* __restrict__ h, const int* __restrict__ mask,
    const float* __restrict__ qr,
    float* __restrict__ P, float* __restrict__ L)
{
    __shared__ float  s_stage[WV][2][TR * CN];   // 64 KB (wave-private dbuf)
    __shared__ float4 s_pb[WV][TR];              // 512 B
    __shared__ float  s_lp[WV][QN];              // 64 B

    const int b    = blockIdx.x >> 4;
    const int sub  = blockIdx.x & (SPB - 1);
    const int w    = threadIdx.x >> 6;
    const int lane = threadIdx.x & 63;
    const int rgrp = lane >> 4;                  // row-in-subpass group (0..3)
    const int l15  = lane & 15;

    const int n0    = (sub * WV + w) * RPW;
    const size_t gn = (size_t)b * NN + n0;
    const float* __restrict__ hb = h + gn * CN;

    // query frags for score channels c = (l15+16k)*4 + i  (scale folded in)
    float4 q4[QN][4];
#pragma unroll
    for (int q = 0; q < QN; ++q)
#pragma unroll
        for (int k = 0; k < 4; ++k) {
            float4 t = *(const float4*)(qr + q * CN + (l15 + 16 * k) * 4);
            t.x *= 0.0625f; t.y *= 0.0625f; t.z *= 0.0625f; t.w *= 0.0625f;
            q4[q][k] = t;
        }

    // mask bits for this wave's 64 rows (one ballot, SGPR-resident)
    const unsigned long long mbits = __ballot(mask[gn + lane] != 0);

    float* const buf0 = &s_stage[w][0][0];
    float* const buf1 = &s_stage[w][1][0];

    float4 acc[QN];
    float  lsum[QN];
#pragma unroll
    for (int q = 0; q < QN; ++q) {
        acc[q] = make_float4(0.f, 0.f, 0.f, 0.f);
        lsum[q] = 0.f;
    }

    float4 vst[TR];

    // ---- prologue: tile0 -> buf0; preload tile1 into regs ----
    LOADT(0);
    STORET(buf0);
    LOADT(1);

    for (int t = 0; t < NT; ++t) {
        float* const bufc = (t & 1) ? buf1 : buf0;
        float* const bufn = (t & 1) ? buf0 : buf1;

        // ---------- score phase: 2 sub-passes x 4 rows ----------
#pragma unroll
        for (int sp = 0; sp < 2; ++sp) {
            const int rt = sp * 4 + rgrp;            // row in tile (per-lane)
            const float* rowp = bufc + rt * CN;
            float s0 = 0.f, s1 = 0.f, s2 = 0.f, s3 = 0.f;
#pragma unroll
            for (int k = 0; k < 4; ++k) {
                const float4 hv = *(const float4*)(rowp + (l15 + 16 * k) * 4);
                s0 += hv.x * q4[0][k].x + hv.y * q4[0][k].y
                    + hv.z * q4[0][k].z + hv.w * q4[0][k].w;
                s1 += hv.x * q4[1][k].x + hv.y * q4[1][k].y
                    + hv.z * q4[1][k].z + hv.w * q4[1][k].w;
                s2 += hv.x * q4[2][k].x + hv.y * q4[2][k].y
                    + hv.z * q4[2][k].z + hv.w * q4[2][k].w;
                s3 += hv.x * q4[3][k].x + hv.y * q4[3][k].y
                    + hv.z * q4[3][k].z + hv.w * q4[3][k].w;
            }
            // reduce across the 16-lane group (4 steps, 4 values pipelined)
#pragma unroll
            for (int off = 1; off <= 8; off <<= 1) {
                s0 += __shfl_xor(s0, off, 64);
                s1 += __shfl_xor(s1, off, 64);
                s2 += __shfl_xor(s2, off, 64);
                s3 += __shfl_xor(s3, off, 64);
            }
            const bool mk = ((mbits >> (t * TR + rt)) & 1ull) != 0;
            float4 pv;
            pv.x = mk ? 0.f : __expf(s0);
            pv.y = mk ? 0.f : __expf(s1);
            pv.z = mk ? 0.f : __expf(s2);
            pv.w = mk ? 0.f : __expf(s3);
            if (l15 == 0) s_pb[w][rt] = pv;
        }

        // ---------- pool phase: lane owns channels 4*lane.. ----------
#pragma unroll
        for (int r = 0; r < TR; ++r) {
            const float4 pv = s_pb[w][r];                       // broadcast
            const float4 hv = *(const float4*)(bufc + r * CN + lane * 4);
            acc[0].x += pv.x * hv.x; acc[0].y += pv.x * hv.y;
            acc[0].z += pv.x * hv.z; acc[0].w += pv.x * hv.w;
            acc[1].x += pv.y * hv.x; acc[1].y += pv.y * hv.y;
            acc[1].z += pv.y * hv.z; acc[1].w += pv.y * hv.w;
            acc[2].x += pv.z * hv.x; acc[2].y += pv.z * hv.y;
            acc[2].z += pv.z * hv.z; acc[2].w += pv.z * hv.w;
            acc[3].x += pv.w * hv.x; acc[3].y += pv.w * hv.y;
            acc[3].z += pv.w * hv.z; acc[3].w += pv.w * hv.w;
            lsum[0] += pv.x; lsum[1] += pv.y;
            lsum[2] += pv.z; lsum[3] += pv.w;
        }

        // ---------- commit tile t+1 to LDS; issue loads for t+2 ----------
        if (t + 1 < NT) {
            STORET(bufn);              // vmcnt wait here (counted, compiler)
            if (t + 2 < NT) LOADT(t + 2);
        }
    }

    // ---- epilogue: stash per-wave results in own stage region, combine ----
    {
        float* part = &s_stage[w][0][0];          // reuse (own region only)
#pragma unroll
        for (int q = 0; q < QN; ++q)
            *(float4*)(part + q * CN + lane * 4) = acc[q];
        if (lane == 0) {
#pragma unroll
            for (int q = 0; q < QN; ++q) s_lp[w][q] = lsum[q];
        }
    }
    __syncthreads();
    {
        const int t = threadIdx.x;                // 256 threads x float4
        float4 o = make_float4(0.f, 0.f, 0.f, 0.f);
#pragma unroll
        for (int ww = 0; ww < WV; ++ww) {
            const float4 v = *(const float4*)(&s_stage[ww][0][0] + t * 4);
            o.x += v.x; o.y += v.y; o.z += v.z; o.w += v.w;
        }
        ((float4*)(P + (size_t)blockIdx.x * (QN * CN)))[t] = o;
        if (t < QN)
            L[blockIdx.x * QN + t] =
                s_lp[0][t] + s_lp[1][t] + s_lp[2][t] + s_lp[3][t];
    }
}

// ---------------------------------------------------------------------------
// Combine SPB block-partials per batch and divide by l (0 if l==0).
// grid = BN blocks x 256 threads; thread = float4 of [q][c].
// ---------------------------------------------------------------------------
__global__ __launch_bounds__(256) void k_div(
    const float* __restrict__ P, const float* __restrict__ L,
    float* __restrict__ out)
{
    const int b = blockIdx.x;
    const int t = threadIdx.x;
    const int q = t >> 6;

    float4 o = make_float4(0.f, 0.f, 0.f, 0.f);
    float  l = 0.f;
#pragma unroll 4
    for (int s = 0; s < SPB; ++s) {
        const float4 pv =
            ((const float4*)(P + (size_t)(b * SPB + s) * (QN * CN)))[t];
        o.x += pv.x; o.y += pv.y; o.z += pv.z; o.w += pv.w;
        l += L[(b * SPB + s) * QN + q];
    }
    const float inv = (l > 0.f) ? 1.f / l : 0.f;
    o.x *= inv; o.y *= inv; o.z *= inv; o.w *= inv;
    ((float4*)(out + (size_t)b * (QN * CN)))[t] = o;
}

extern "C" void kernel_launch(void* const* d_in, const int* in_sizes, int n_in,
                              void* d_out, int out_size, void* d_ws, size_t ws_size,
                              hipStream_t stream) {
    const float* h    = (const float*)d_in[0];
    const int*   mask = (const int*)d_in[1];
    const float* qr   = (const float*)d_in[2];
    float*       out  = (float*)d_out;

    float* P = (float*)d_ws;                            // [512][Q*C] = 2 MB
    float* L = P + (size_t)BN * SPB * QN * CN;          // [512][Q]   = 8 KB

    k_fused<<<BN * SPB, 256, 0, stream>>>(h, mask, qr, P, L);
    k_div  <<<BN, 256, 0, stream>>>(P, L, out);
}